// Round 19
// baseline (230.201 us; speedup 1.0000x reference)
//
#include <hip/hip_runtime.h>

#define NPTS 4096
#define BATCH 8
#define G 24                         // grid resolution per axis
#define NCELL (G * G * G)            // 13824 cells
#define NCELL_PAD 14336              // 1024 * 14 (scan padding)
#define CPT 14                       // cells per thread in the scan
#define HCELL 0.41666667f            // 10/24
#define INVH 2.4f                    // 24/10
#define FBLK 1024

__device__ __forceinline__ int cellof(float v) {
  int c = (int)floorf((v + 5.0f) * INVH);
  return min(G - 1, max(0, c));
}

// ---------------------------------------------------------------------------
// Kernel A: counting-sort build, one block per (b, which). LDS histogram over
// 24^3 cells, block-wide exclusive scan, scatter points (as float4) into
// cell-sorted order. Within-cell order is atomic-race-dependent, but every
// consumer takes an exact MIN over the full cell -> order-independent, so the
// final output is bit-deterministic. Also zeroes the finalize ticket.
// ---------------------------------------------------------------------------
__global__ __launch_bounds__(1024) void build_kernel(
    const float* __restrict__ X, const float* __restrict__ Y,
    float4* __restrict__ sorted, int* __restrict__ cell_start,
    unsigned int* __restrict__ ticket) {
  if (blockIdx.x == 0 && blockIdx.y == 0 && threadIdx.x == 0) {
    __hip_atomic_store(ticket, 0u, __ATOMIC_RELAXED, __HIP_MEMORY_SCOPE_AGENT);
  }
  const int which = blockIdx.x;  // 0 -> X, 1 -> Y
  const int b     = blockIdx.y;
  const float* pb = (which ? Y : X) + (size_t)b * NPTS * 3;

  __shared__ unsigned int cnt[NCELL_PAD];  // 56 KB
  __shared__ unsigned int wtot[16];

  for (int i = threadIdx.x; i < NCELL_PAD; i += 1024) cnt[i] = 0u;
  __syncthreads();

  // count; keep this thread's 4 points in registers
  int pc[4];
  float ppx[4], ppy[4], ppz[4];
#pragma unroll
  for (int k = 0; k < 4; ++k) {
    const int i = threadIdx.x + k * 1024;
    float x = pb[3 * i], y = pb[3 * i + 1], z = pb[3 * i + 2];
    int c = (cellof(z) * G + cellof(y)) * G + cellof(x);
    pc[k] = c; ppx[k] = x; ppy[k] = y; ppz[k] = z;
    atomicAdd(&cnt[c], 1u);
  }
  __syncthreads();

  // blocked exclusive scan: thread t owns cnt[t*CPT .. t*CPT+CPT)
  const int base = threadIdx.x * CPT;
  unsigned int v[CPT], run = 0u;
#pragma unroll
  for (int k = 0; k < CPT; ++k) v[k] = cnt[base + k];
#pragma unroll
  for (int k = 0; k < CPT; ++k) { unsigned int t = v[k]; v[k] = run; run += t; }
  const int lane = threadIdx.x & 63, wid = threadIdx.x >> 6;
  unsigned int inc = run;
  for (int off = 1; off <= 32; off <<= 1) {
    unsigned int n = __shfl_up((int)inc, off, 64);
    if (lane >= off) inc += n;
  }
  if (lane == 63) wtot[wid] = inc;
  __syncthreads();  // also guarantees all v[] reads happened before overwrite
  unsigned int wbase = 0u;
  for (int i = 0; i < wid; ++i) wbase += wtot[i];
  const unsigned int texcl = wbase + inc - run;
#pragma unroll
  for (int k = 0; k < CPT; ++k) cnt[base + k] = texcl + v[k];
  __syncthreads();

  // publish cell_start (exclusive prefix) + sentinel
  int* cs = cell_start + (size_t)(b * 2 + which) * (NCELL + 1);
  for (int i = threadIdx.x; i < NCELL; i += 1024) cs[i] = (int)cnt[i];
  if (threadIdx.x == 0) cs[NCELL] = NPTS;
  __syncthreads();  // cs copy must finish before scatter corrupts cnt

  // scatter
  float4* sb = sorted + (size_t)(b * 2 + which) * NPTS;
#pragma unroll
  for (int k = 0; k < 4; ++k) {
    unsigned int slot = atomicAdd(&cnt[pc[k]], 1u);
    sb[slot] = make_float4(ppx[k], ppy[k], ppz[k], 0.0f);
  }
}

// ---------------------------------------------------------------------------
// Kernel B: exact NN query via expanding Chebyshev shells. Stop before shell
// s when ((s-1)*h)^2 >= d2min: any point assigned to a cell at L-inf cell
// distance s is >= (s-1)*h away (clamping is 1-Lipschitz, so this lower
// bound holds even for out-of-range coordinates). Queries in ORIGINAL index
// order; dmin[w][qi] gets the exact min -> deterministic.
// grid = (16 qchunks, 16 w), 256 threads.
// ---------------------------------------------------------------------------
__global__ __launch_bounds__(256) void query_kernel(
    const float* __restrict__ X, const float* __restrict__ Y,
    const float4* __restrict__ sorted, const int* __restrict__ cell_start,
    float* __restrict__ dmin) {
  const int w   = blockIdx.y;    // dir*8 + b
  const int dir = w >> 3;
  const int b   = w & 7;
  const float* qsrc = dir ? Y : X;            // queries
  const int whichc  = dir ? 0 : 1;            // candidates = other set
  const float4* sb = sorted + (size_t)(b * 2 + whichc) * NPTS;
  const int* cs = cell_start + (size_t)(b * 2 + whichc) * (NCELL + 1);

  const int qi = blockIdx.x * 256 + threadIdx.x;
  const float* qp = qsrc + ((size_t)b * NPTS + qi) * 3;
  const float qx = qp[0], qy = qp[1], qz = qp[2];
  const int cx = cellof(qx), cy = cellof(qy), cz = cellof(qz);

  float d2min = 3.4e38f;

#define SCANCELL(xx, yy, zz)                                                  \
  {                                                                           \
    const int c = (((zz)*G + (yy)) * G + (xx));                               \
    const int st = cs[c], en = cs[c + 1];                                     \
    for (int k = st; k < en; ++k) {                                           \
      float4 p = sb[k];                                                       \
      float dx = qx - p.x, dy = qy - p.y, dz = qz - p.z;                      \
      d2min = fminf(d2min, fmaf(dx, dx, fmaf(dy, dy, dz * dz)));              \
    }                                                                         \
  }

  for (int s = 0; s < G; ++s) {
    if (s >= 2) {
      float lb = (float)(s - 1) * HCELL;
      if (lb * lb >= d2min) break;
    }
    const int zlo = max(cz - s, 0), zhi = min(cz + s, G - 1);
    const int ylo = max(cy - s, 0), yhi = min(cy + s, G - 1);
    const int xlo = max(cx - s, 0), xhi = min(cx + s, G - 1);
    for (int z = zlo; z <= zhi; ++z) {
      const bool zface = (z == cz - s) || (z == cz + s);
      for (int y = ylo; y <= yhi; ++y) {
        const bool face = zface || (y == cy - s) || (y == cy + s);
        if (face) {
          for (int x = xlo; x <= xhi; ++x) SCANCELL(x, y, z);
        } else {
          if (cx - s >= 0) SCANCELL(cx - s, y, z);
          if (s > 0 && cx + s < G) SCANCELL(cx + s, y, z);
        }
      }
    }
  }
#undef SCANCELL

  dmin[(size_t)w * NPTS + qi] = d2min;
}

// ---------------------------------------------------------------------------
// Kernel C: finalize, 16 blocks x 1024 threads, block w = (dir,b). Each
// thread owns one float4 of dmin; block-wide {sum,ssq} (wave shuffle +
// 16-wave LDS tree), one-pass ddof=1 var, strict mask (v-mean > -0.5*std),
// fixed-order reductions -> res[w]; last block via ticket sums res[0..15]
// in fixed index order -> out[0]. Bit-deterministic, no memset.
// ---------------------------------------------------------------------------
__global__ __launch_bounds__(FBLK) void finalize_kernel(
    const float* __restrict__ dmin, float* __restrict__ res,
    unsigned int* __restrict__ ticket, float* __restrict__ out) {
  const int w    = blockIdx.x;
  const int wid  = threadIdx.x >> 6;
  const int lane = threadIdx.x & 63;

  __shared__ float rA[16], rB[16], rC[16], rD[16];

  const float4* pv = (const float4*)(dmin + (size_t)w * NPTS);
  float4 m = pv[threadIdx.x];
  float sum = (m.x + m.y) + (m.z + m.w);
  float ssq = (m.x * m.x + m.y * m.y) + (m.z * m.z + m.w * m.w);

  for (int off = 32; off; off >>= 1) sum += __shfl_xor(sum, off, 64);
  for (int off = 32; off; off >>= 1) ssq += __shfl_xor(ssq, off, 64);
  if (lane == 0) { rA[wid] = sum; rB[wid] = ssq; }
  __syncthreads();
  sum = ((rA[0] + rA[1]) + (rA[2] + rA[3])) + ((rA[4] + rA[5]) + (rA[6] + rA[7]))
      + ((rA[8] + rA[9]) + (rA[10] + rA[11])) + ((rA[12] + rA[13]) + (rA[14] + rA[15]));
  ssq = ((rB[0] + rB[1]) + (rB[2] + rB[3])) + ((rB[4] + rB[5]) + (rB[6] + rB[7]))
      + ((rB[8] + rB[9]) + (rB[10] + rB[11])) + ((rB[12] + rB[13]) + (rB[14] + rB[15]));
  const float mean = sum / (float)NPTS;
  const float var  = (ssq - (float)NPTS * mean * mean) / (float)(NPTS - 1);
  const float neg_thr = -0.5f * sqrtf(fmaxf(var, 0.0f));

  float ksum = 0.0f, kcnt = 0.0f;
  if (m.x - mean > neg_thr) { ksum += m.x; kcnt += 1.0f; }
  if (m.y - mean > neg_thr) { ksum += m.y; kcnt += 1.0f; }
  if (m.z - mean > neg_thr) { ksum += m.z; kcnt += 1.0f; }
  if (m.w - mean > neg_thr) { ksum += m.w; kcnt += 1.0f; }
  for (int off = 32; off; off >>= 1) ksum += __shfl_xor(ksum, off, 64);
  for (int off = 32; off; off >>= 1) kcnt += __shfl_xor(kcnt, off, 64);
  if (lane == 0) { rC[wid] = ksum; rD[wid] = kcnt; }
  __syncthreads();

  if (threadIdx.x == 0) {
    ksum = ((rC[0] + rC[1]) + (rC[2] + rC[3])) + ((rC[4] + rC[5]) + (rC[6] + rC[7]))
         + ((rC[8] + rC[9]) + (rC[10] + rC[11])) + ((rC[12] + rC[13]) + (rC[14] + rC[15]));
    kcnt = ((rD[0] + rD[1]) + (rD[2] + rD[3])) + ((rD[4] + rD[5]) + (rD[6] + rD[7]))
         + ((rD[8] + rD[9]) + (rD[10] + rD[11])) + ((rD[12] + rD[13]) + (rD[14] + rD[15]));
    __hip_atomic_store(&res[w], ksum / kcnt, __ATOMIC_RELAXED,
                       __HIP_MEMORY_SCOPE_AGENT);
    __threadfence();  // release: res[w] visible before ticket bump
    unsigned int old = atomicAdd(ticket, 1u);
    if (old == 15u) {
      __threadfence();  // acquire: all res[] visible
      float tot = 0.0f;
      for (int i = 0; i < 16; ++i) {
        tot += __hip_atomic_load(&res[i], __ATOMIC_RELAXED,
                                 __HIP_MEMORY_SCOPE_AGENT);
      }
      out[0] = tot / (float)BATCH;
    }
  }
}

extern "C" void kernel_launch(void* const* d_in, const int* in_sizes, int n_in,
                              void* d_out, int out_size, void* d_ws, size_t ws_size,
                              hipStream_t stream) {
  const float* x = (const float*)d_in[0];
  const float* y = (const float*)d_in[1];
  float* out = (float*)d_out;

  char* ws = (char*)d_ws;
  float4* sorted    = (float4*)ws;                           // 16*4096*16B = 1 MB
  int*   cell_start = (int*)(ws + (1 << 20));                // 16*13825*4B ~ 864 KB
  float* dmin = (float*)(ws + (1 << 20) + 16 * (NCELL + 1) * 4);  // 256 KB (16B-aligned)
  float* res  = dmin + (size_t)2 * BATCH * NPTS;             // 16 floats
  unsigned int* ticket = (unsigned int*)(res + 16);          // 1 uint

  dim3 gA(2, BATCH);        // 16 blocks
  build_kernel<<<gA, 1024, 0, stream>>>(x, y, sorted, cell_start, ticket);
  dim3 gB(NPTS / 256, 16);  // 256 blocks
  query_kernel<<<gB, 256, 0, stream>>>(x, y, sorted, cell_start, dmin);
  finalize_kernel<<<16, FBLK, 0, stream>>>(dmin, res, ticket, out);
}

// Round 20
// 32.860 us; speedup vs baseline: 7.0056x; 7.0056x over previous
//
#include <hip/hip_runtime.h>

#define NPTS 4096
#define BATCH 8
#define BLK 256
#define PPT 8                        // p-points per thread
#define NPB (BLK * PPT)              // 2048 p-points per block
#define MCH 256                      // q-points staged in LDS per block
#define NCHUNK (NPTS / MCH)          // 16
#define PGRP (NPTS / NPB)            // 2
#define FREG (NPTS / 4 / BLK)        // 4 float4 per finalize thread

// ---------------------------------------------------------------------------
// Kernel 1: partial min over one q-chunk. Measured champion (R16, 32.6 us):
// 512 blocks, MCH=256, PPT=8, scalar fmaf/min3 AoS math, depth-1 register
// prefetch. LDS holds (-2qx,-2qy,-2qz,|q|^2); |p|^2 folded out of the loop:
// d' = |q|^2 - 2 p.q (3 FMA/pair), final = min(d') + |p|^2.
// ---------------------------------------------------------------------------
__global__ __launch_bounds__(BLK, 2) void dmin_kernel(
    const float* __restrict__ X, const float* __restrict__ Y,
    float* __restrict__ partial, unsigned int* __restrict__ ticket) {
  if (blockIdx.x == 0 && blockIdx.y == 0 && blockIdx.z == 0 &&
      threadIdx.x == 0) {
    __hip_atomic_store(ticket, 0u, __ATOMIC_RELAXED, __HIP_MEMORY_SCOPE_AGENT);
  }

  const int pg    = blockIdx.x;
  const int b     = blockIdx.y;
  const int chunk = blockIdx.z & (NCHUNK - 1);
  const int dir   = blockIdx.z >> 4;
  const float* pts = dir ? Y : X;  // set we compute mins for
  const float* oth = dir ? X : Y;  // set we min over

  __shared__ float4 s[MCH];  // 4 KB, AoS (-2qx,-2qy,-2qz,|q|^2)
  const float* othb = oth + ((size_t)b * NPTS + (size_t)chunk * MCH) * 3;
  {
    const int i = threadIdx.x;  // MCH == BLK: one q per thread
    float qx = othb[3 * i], qy = othb[3 * i + 1], qz = othb[3 * i + 2];
    s[i] = make_float4(-2.f * qx, -2.f * qy, -2.f * qz,
                       qx * qx + qy * qy + qz * qz);
  }
  __syncthreads();

  const int n0 = pg * NPB + threadIdx.x * PPT;  // 8 consecutive p-points
  const float4* pv4 = (const float4*)(pts + ((size_t)b * NPTS + n0) * 3);
  const float4 A = pv4[0], B = pv4[1], C = pv4[2];
  const float4 D = pv4[3], E = pv4[4], F = pv4[5];
  float px[PPT], py[PPT], pz[PPT];
  px[0] = A.x; py[0] = A.y; pz[0] = A.z;
  px[1] = A.w; py[1] = B.x; pz[1] = B.y;
  px[2] = B.z; py[2] = B.w; pz[2] = C.x;
  px[3] = C.y; py[3] = C.z; pz[3] = C.w;
  px[4] = D.x; py[4] = D.y; pz[4] = D.z;
  px[5] = D.w; py[5] = E.x; pz[5] = E.y;
  px[6] = E.z; py[6] = E.w; pz[6] = F.x;
  px[7] = F.y; py[7] = F.z; pz[7] = F.w;

  float acc[2 * PPT];
#pragma unroll
  for (int i = 0; i < 2 * PPT; ++i) acc[i] = 3.4e38f;

#define COMPUTE(q0, q1, q2, q3)                                               \
  {                                                                           \
    _Pragma("unroll")                                                         \
    for (int pp = 0; pp < PPT; ++pp) {                                        \
      float d0 = fmaf(px[pp], q0.x,                                           \
                 fmaf(py[pp], q0.y, fmaf(pz[pp], q0.z, q0.w)));               \
      float d1 = fmaf(px[pp], q1.x,                                           \
                 fmaf(py[pp], q1.y, fmaf(pz[pp], q1.z, q1.w)));               \
      float d2 = fmaf(px[pp], q2.x,                                           \
                 fmaf(py[pp], q2.y, fmaf(pz[pp], q2.z, q2.w)));               \
      float d3 = fmaf(px[pp], q3.x,                                           \
                 fmaf(py[pp], q3.y, fmaf(pz[pp], q3.z, q3.w)));               \
      acc[2 * pp]     = fminf(fminf(acc[2 * pp], d0), d1);     /* v_min3 */   \
      acc[2 * pp + 1] = fminf(fminf(acc[2 * pp + 1], d2), d3); /* v_min3 */   \
    }                                                                         \
  }

  float4 c0 = s[0], c1 = s[1], c2 = s[2], c3 = s[3];
#pragma unroll 2
  for (int m = 0; m < MCH - 4; m += 4) {
    float4 t0 = s[m + 4], t1 = s[m + 5], t2 = s[m + 6], t3 = s[m + 7];
    COMPUTE(c0, c1, c2, c3);
    c0 = t0; c1 = t1; c2 = t2; c3 = t3;
  }
  COMPUTE(c0, c1, c2, c3);
#undef COMPUTE

  float r[PPT];
#pragma unroll
  for (int pp = 0; pp < PPT; ++pp) {
    float c = px[pp] * px[pp] + py[pp] * py[pp] + pz[pp] * pz[pp];
    r[pp] = fminf(acc[2 * pp], acc[2 * pp + 1]) + c;
  }
  float* dst = &partial[(((size_t)chunk * 2 + dir) * BATCH + b) * NPTS + n0];
  ((float4*)dst)[0] = make_float4(r[0], r[1], r[2], r[3]);
  ((float4*)dst)[1] = make_float4(r[4], r[5], r[6], r[7]);
}

// ---------------------------------------------------------------------------
// Kernel 2: 16 blocks, block w = (dir,b). 16-way chunk-min in registers,
// fused sum/ssq (one-pass ddof=1 var), strict mask (v-mean > -0.5*std),
// fixed-order reductions -> res[w]. Last block (ticket) sums res[0..15] in
// fixed index order -> out[0]. No memset, no spin-wait, bit-deterministic.
// ---------------------------------------------------------------------------
__global__ __launch_bounds__(BLK) void finalize_kernel(
    const float* __restrict__ partial, float* __restrict__ res,
    unsigned int* __restrict__ ticket, float* __restrict__ out) {
  const int w    = blockIdx.x;   // dir*8 + b
  const int dir  = w >> 3;
  const int b    = w & 7;
  const int wid  = threadIdx.x >> 6;
  const int lane = threadIdx.x & 63;

  __shared__ float rA[4], rB[4], rC[4], rD[4];

  const float4* pv = (const float4*)partial;
  const size_t vbase = ((size_t)dir * BATCH + b) * (NPTS / 4);
  const size_t cstr  = (size_t)2 * BATCH * (NPTS / 4);

  float4 mreg[FREG];  // this thread's 4 minned float4s, kept in registers
  float sum = 0.0f, ssq = 0.0f;
#pragma unroll
  for (int k = 0; k < FREG; ++k) {
    const int i = threadIdx.x + k * BLK;
    float4 m = pv[vbase + i];
#pragma unroll
    for (int c = 1; c < NCHUNK; ++c) {
      float4 t = pv[vbase + (size_t)c * cstr + i];
      m.x = fminf(m.x, t.x); m.y = fminf(m.y, t.y);
      m.z = fminf(m.z, t.z); m.w = fminf(m.w, t.w);
    }
    mreg[k] = m;
    sum += (m.x + m.y) + (m.z + m.w);
    ssq += (m.x * m.x + m.y * m.y) + (m.z * m.z + m.w * m.w);
  }
  for (int off = 32; off; off >>= 1) sum += __shfl_xor(sum, off, 64);
  for (int off = 32; off; off >>= 1) ssq += __shfl_xor(ssq, off, 64);
  if (lane == 0) { rA[wid] = sum; rB[wid] = ssq; }
  __syncthreads();
  sum = ((rA[0] + rA[1]) + (rA[2] + rA[3]));  // fixed order: deterministic
  ssq = ((rB[0] + rB[1]) + (rB[2] + rB[3]));
  const float mean = sum / (float)NPTS;
  const float var  = (ssq - (float)NPTS * mean * mean) / (float)(NPTS - 1);
  const float neg_thr = -0.5f * sqrtf(fmaxf(var, 0.0f));

  float ksum = 0.0f, kcnt = 0.0f;
#pragma unroll
  for (int k = 0; k < FREG; ++k) {
    float4 t = mreg[k];
    if (t.x - mean > neg_thr) { ksum += t.x; kcnt += 1.0f; }
    if (t.y - mean > neg_thr) { ksum += t.y; kcnt += 1.0f; }
    if (t.z - mean > neg_thr) { ksum += t.z; kcnt += 1.0f; }
    if (t.w - mean > neg_thr) { ksum += t.w; kcnt += 1.0f; }
  }
  for (int off = 32; off; off >>= 1) ksum += __shfl_xor(ksum, off, 64);
  for (int off = 32; off; off >>= 1) kcnt += __shfl_xor(kcnt, off, 64);
  if (lane == 0) { rC[wid] = ksum; rD[wid] = kcnt; }
  __syncthreads();

  if (threadIdx.x == 0) {
    ksum = ((rC[0] + rC[1]) + (rC[2] + rC[3]));
    kcnt = ((rD[0] + rD[1]) + (rD[2] + rD[3]));
    __hip_atomic_store(&res[w], ksum / kcnt, __ATOMIC_RELAXED,
                       __HIP_MEMORY_SCOPE_AGENT);
    __threadfence();  // release: res[w] visible before ticket bump
    unsigned int old = atomicAdd(ticket, 1u);  // device-scope by default
    if (old == 15u) {
      __threadfence();  // acquire: all res[] writes visible
      float tot = 0.0f;
      for (int i = 0; i < 16; ++i) {  // fixed order: bit-deterministic
        tot += __hip_atomic_load(&res[i], __ATOMIC_RELAXED,
                                 __HIP_MEMORY_SCOPE_AGENT);
      }
      out[0] = tot / (float)BATCH;
    }
  }
}

extern "C" void kernel_launch(void* const* d_in, const int* in_sizes, int n_in,
                              void* d_out, int out_size, void* d_ws, size_t ws_size,
                              hipStream_t stream) {
  const float* x = (const float*)d_in[0];
  const float* y = (const float*)d_in[1];
  float* out = (float*)d_out;
  float* partial = (float*)d_ws;                       // 16*2*8*4096*4B = 4 MB
  float* res = partial + (size_t)NCHUNK * 2 * BATCH * NPTS;  // 16 floats
  unsigned int* ticket = (unsigned int*)(res + 16);          // 1 uint

  dim3 g1(PGRP, BATCH, 2 * NCHUNK);
  dmin_kernel<<<g1, BLK, 0, stream>>>(x, y, partial, ticket);
  finalize_kernel<<<16, BLK, 0, stream>>>(partial, res, ticket, out);
}